// Round 7
// baseline (479.142 us; speedup 1.0000x reference)
//
#include <hip/hip_runtime.h>

#define SEQ   200
#define BATCH 4096
#define EMB   100
#define HID   300
#define NH1   256
#define BM    16
#define NFRAG 13             // K = 416: xe k=0..99 | zeros 100..111 | h k=112..411 | zeros
#define FRB   14             // allocated frag blocks (k up to 447)
#define FB    1024           // bytes per frag block (32 k x 16 rows x 2B)
#define BUFB  (FRB * FB)
#define NT    5              // col-tiles per wave; 4 waves * 5 * 16 = 320 cols (300 real + pad)
#define NHF   10
#define H1P   260
#define PD    5              // LDS read-pipeline depth

typedef _Float16 half8 __attribute__((ext_vector_type(8)));
typedef _Float16 half4h __attribute__((ext_vector_type(4)));
typedef float floatx4 __attribute__((ext_vector_type(4)));

__device__ __forceinline__ float fast_tanh(float x) {
    float e = __expf(2.0f * x);
    float r = __builtin_amdgcn_rcpf(e + 1.0f);
    return 1.0f - 2.0f * r;
}

// frag-space byte offset of (batch row m, combined-k k)
__device__ __forceinline__ int fragoff(int m, int k) {
    return (k >> 5) * FB + ((k >> 3) & 3) * 256 + m * 16 + (k & 7) * 2;
}

__global__ void __launch_bounds__(256, 1)
rnn_fused(const int* __restrict__ x, const float* __restrict__ emb,
          const float* __restrict__ W_ih, const float* __restrict__ b_ih,
          const float* __restrict__ W_hh, const float* __restrict__ b_hh,
          const float* __restrict__ W1, const float* __restrict__ b1,
          const float* __restrict__ W2, const float* __restrict__ b2,
          float* __restrict__ out)
{
    __shared__ __align__(16) _Float16 uf[2][FRB][512];  // frag-order, double-buffered
    __shared__ int      xs[SEQ * BM];
    __shared__ float    h1s[BM][H1P];

    const int tid  = threadIdx.x;
    const int lane = tid & 63;
    const int w    = tid >> 6;           // wave 0..3
    const int ln15 = lane & 15;
    const int q    = lane >> 4;
    const int row0 = blockIdx.x * BM;
    const int t0   = 5 * w;              // tiles t0..t0+4 (tile 19 = zero pad)

    // zero both u buffers (pads must stay zero)
    for (int i = tid; i < 2 * FRB * 512 / 2; i += 256) ((unsigned int*)uf)[i] = 0u;
    for (int i = tid; i < SEQ * BM; i += 256)
        xs[i] = x[(size_t)(i >> 4) * BATCH + row0 + (i & 15)];

    // ---- W resident in registers (A-operand: lane ln15 = row n, k = kk*32+q*8+j)
    half8   Wb[NT][NFRAG];
    floatx4 biasv[NT];
#pragma unroll
    for (int tt = 0; tt < NT; ++tt) {
        const int nb = (t0 + tt) * 16;
#pragma unroll
        for (int r = 0; r < 4; ++r) {
            const int col = nb + 4 * q + r;
            biasv[tt][r] = (col < HID) ? (b_ih[col] + b_hh[col]) : 0.0f;
        }
        const int n = nb + ln15;
#pragma unroll
        for (int kk = 0; kk < NFRAG; ++kk) {
            union { half8 h; unsigned int d[4]; } cv;
#pragma unroll
            for (int j = 0; j < 8; ++j) {
                const int k = kk * 32 + q * 8 + j;
                float v = 0.0f;
                if (n < HID) {
                    if (k < EMB)                        v = W_ih[n * EMB + k];
                    else if (k >= 112 && k < 112 + HID) v = W_hh[n * HID + (k - 112)];
                }
                cv.h[j] = (_Float16)v;
            }
            asm volatile("" : "+v"(cv.d[0]), "+v"(cv.d[1]), "+v"(cv.d[2]), "+v"(cv.d[3]));
            Wb[tt][kk] = cv.h;
        }
    }

    // ---- precomputed LDS byte offsets
    char* ub = (char*)uf;
    const int rdo = lane * 16;
    int hwo[NT];
#pragma unroll
    for (int tt = 0; tt < NT; ++tt)
        hwo[tt] = fragoff(ln15, 112 + (t0 + tt) * 16 + 4 * q);
    // xe stager: thread handles chunk c0 = tid, and c1 = tid+256 (if < 400)
    const int c0 = tid,      c0r = c0 / 25, c0c = c0 - c0r * 25;
    const int c1 = tid + 256, c1r = c1 / 25, c1c = c1 - c1r * 25;
    const bool has1 = (c1 < 400);
    const int xwo0 = fragoff(c0r, c0c * 4);
    const int xwo1 = has1 ? fragoff(c1r, c1c * 4) : 0;
    __syncthreads();

    // ---- xe_0 directly to buffer 0; issue xe_1 loads into pf[1]
    float4 pf0[2][2];  // [set][chunk]; set (t&1) reloaded at top of step t for xe_{t+2}
    {
        const float4 f0 = ((const float4*)emb)[(size_t)xs[c0r] * 25 + c0c];
        float4 f1;
        if (has1) f1 = ((const float4*)emb)[(size_t)xs[c1r] * 25 + c1c];
        half4h hv; hv[0] = (_Float16)f0.x; hv[1] = (_Float16)f0.y;
                   hv[2] = (_Float16)f0.z; hv[3] = (_Float16)f0.w;
        *(half4h*)(ub + xwo0) = hv;
        if (has1) {
            half4h h1; h1[0] = (_Float16)f1.x; h1[1] = (_Float16)f1.y;
                       h1[2] = (_Float16)f1.z; h1[3] = (_Float16)f1.w;
            *(half4h*)(ub + xwo1) = h1;
        }
        // xe_1 loads (consumed at end of step 0)
        pf0[1][0] = ((const float4*)emb)[(size_t)xs[1 * BM + c0r] * 25 + c0c];
        if (has1) pf0[1][1] = ((const float4*)emb)[(size_t)xs[1 * BM + c1r] * 25 + c1c];
    }
    __syncthreads();

#pragma unroll 2
    for (int t = 0; t < SEQ; ++t) {
        const int p = t & 1;
        const char* rb = ub + p * BUFB + rdo;
        char*       wb = ub + (1 - p) * BUFB;

        // issue xe_{t+2} gather into set p — ~2 steps of latency cover
        if (t + 2 < SEQ) {
            pf0[p][0] = ((const float4*)emb)[(size_t)xs[(t + 2) * BM + c0r] * 25 + c0c];
            if (has1) pf0[p][1] = ((const float4*)emb)[(size_t)xs[(t + 2) * BM + c1r] * 25 + c1c];
        }

        floatx4 acc[NT];
#pragma unroll
        for (int tt = 0; tt < NT; ++tt) acc[tt] = biasv[tt];

        half8 af[NFRAG];
#pragma unroll
        for (int kk = 0; kk < PD; ++kk) af[kk] = *(const half8*)(rb + kk * FB);
#pragma unroll
        for (int kk = 0; kk < NFRAG; ++kk) {
            if (kk + PD < NFRAG) af[kk + PD] = *(const half8*)(rb + (kk + PD) * FB);
#pragma unroll
            for (int tt = 0; tt < NT; ++tt)
                acc[tt] = __builtin_amdgcn_mfma_f32_16x16x32_f16(Wb[tt][kk], af[kk], acc[tt], 0, 0, 0);
        }

        // write xe_{t+1} (loaded during step t-1) into the next buffer
        if (t + 1 < SEQ) {
            const float4 f0 = pf0[1 - p][0];
            half4h hv; hv[0] = (_Float16)f0.x; hv[1] = (_Float16)f0.y;
                       hv[2] = (_Float16)f0.z; hv[3] = (_Float16)f0.w;
            *(half4h*)(wb + xwo0) = hv;
            if (has1) {
                const float4 f1 = pf0[1 - p][1];
                half4h h1; h1[0] = (_Float16)f1.x; h1[1] = (_Float16)f1.y;
                           h1[2] = (_Float16)f1.z; h1[3] = (_Float16)f1.w;
                *(half4h*)(wb + xwo1) = h1;
            }
        }
        // tanh + packed h-writes (D transposed: lane ln15 = batch row, 4 consecutive cols)
#pragma unroll
        for (int tt = 0; tt < NT; ++tt) {
            half4h hv;
#pragma unroll
            for (int r = 0; r < 4; ++r) hv[r] = (_Float16)fast_tanh(acc[tt][r]);
            *(half4h*)(wb + hwo[tt]) = hv;
        }
        __syncthreads();
    }

    // ---- head: h1 = relu(h @ W1^T + b1); final h in buffer 0 (frag layout)
    {
        const int hro = fragoff(ln15, 112 + q * 8);
        floatx4 hacc[4];
        int ncol[4];
#pragma unroll
        for (int tt = 0; tt < 4; ++tt) {
            const int n = (4 * w + tt) * 16 + ln15;
            ncol[tt] = n;
            const float b = b1[n];
            hacc[tt][0] = b; hacc[tt][1] = b; hacc[tt][2] = b; hacc[tt][3] = b;
        }
#pragma unroll
        for (int kk = 0; kk < NHF; ++kk) {
            const half8 a = *(const half8*)(ub + hro + kk * FB);
#pragma unroll
            for (int tt = 0; tt < 4; ++tt) {
                half8 bv;
#pragma unroll
                for (int j = 0; j < 8; ++j) {
                    const int k = kk * 32 + q * 8 + j;
                    bv[j] = (_Float16)((k < HID) ? W1[ncol[tt] * HID + k] : 0.0f);
                }
                hacc[tt] = __builtin_amdgcn_mfma_f32_16x16x32_f16(bv, a, hacc[tt], 0, 0, 0);
            }
        }
        // D transposed: lane ln15 = batch row, cols (4w+tt)*16 + 4q + r
#pragma unroll
        for (int tt = 0; tt < 4; ++tt) {
            float4 fv;
            fv.x = fmaxf(hacc[tt][0], 0.0f); fv.y = fmaxf(hacc[tt][1], 0.0f);
            fv.z = fmaxf(hacc[tt][2], 0.0f); fv.w = fmaxf(hacc[tt][3], 0.0f);
            *(float4*)&h1s[ln15][(4 * w + tt) * 16 + 4 * q] = fv;
        }
    }
    __syncthreads();

    // ---- out = h1 @ W2^T + b2: 16 rows x 2 cols
    if (tid < 32) {
        const int r = tid & 15, o = tid >> 4;
        float a = b2[o];
        const float* ww = W2 + (size_t)o * NH1;
        for (int k = 0; k < NH1; ++k) a += h1s[r][k] * ww[k];
        out[(size_t)(row0 + r) * 2 + o] = a;
    }
}

extern "C" void kernel_launch(void* const* d_in, const int* in_sizes, int n_in,
                              void* d_out, int out_size, void* d_ws, size_t ws_size,
                              hipStream_t stream) {
    const int*   x    = (const int*)d_in[0];
    const float* emb  = (const float*)d_in[1];
    const float* W_ih = (const float*)d_in[2];
    const float* b_ih = (const float*)d_in[3];
    const float* W_hh = (const float*)d_in[4];
    const float* b_hh = (const float*)d_in[5];
    const float* W1   = (const float*)d_in[6];
    const float* b1   = (const float*)d_in[7];
    const float* W2   = (const float*)d_in[8];
    const float* b2   = (const float*)d_in[9];
    float* outp = (float*)d_out;

    hipLaunchKernelGGL(rnn_fused, dim3(BATCH / BM), dim3(256), 0, stream,
                       x, emb, W_ih, b_ih, W_hh, b_hh, W1, b1, W2, b2, outp);
}

// Round 8
// 448.143 us; speedup vs baseline: 1.0692x; 1.0692x over previous
//
#include <hip/hip_runtime.h>

#define SEQ   200
#define BATCH 4096
#define EMB   100
#define HID   300
#define NH1   256
#define BM    16
#define NFRAG 13             // K = 416: xe k=0..99 | zeros 100..111 | h k=112..411 | zeros
#define FRB   14             // allocated frag blocks (k up to 447)
#define FB    1024           // bytes per frag block (32 k x 16 rows x 2B)
#define BUFB  (FRB * FB)
#define NTMAX 3
#define NHF   10
#define H1P   260
#define PD    3              // LDS read-pipeline depth

typedef _Float16 half8 __attribute__((ext_vector_type(8)));
typedef _Float16 half4h __attribute__((ext_vector_type(4)));
typedef float floatx4 __attribute__((ext_vector_type(4)));

__device__ __forceinline__ float fast_tanh(float x) {
    float e = __expf(2.0f * x);
    float r = __builtin_amdgcn_rcpf(e + 1.0f);
    return 1.0f - 2.0f * r;
}

// frag-space byte offset of (batch row m, combined-k k)
__device__ __forceinline__ int fragoff(int m, int k) {
    return (k >> 5) * FB + ((k >> 3) & 3) * 256 + m * 16 + (k & 7) * 2;
}

__global__ void __launch_bounds__(512)
rnn_fused(const int* __restrict__ x, const float* __restrict__ emb,
          const float* __restrict__ W_ih, const float* __restrict__ b_ih,
          const float* __restrict__ W_hh, const float* __restrict__ b_hh,
          const float* __restrict__ W1, const float* __restrict__ b1,
          const float* __restrict__ W2, const float* __restrict__ b2,
          float* __restrict__ out)
{
    __shared__ __align__(16) _Float16 uf[2][FRB][512];  // frag-order, double-buffered
    __shared__ float h1s[BM][H1P];

    const int tid  = threadIdx.x;
    const int lane = tid & 63;
    const int w    = tid >> 6;
    const int ln15 = lane & 15;
    const int q    = lane >> 4;
    const int row0 = blockIdx.x * BM;

    // 19 tiles of 16 cols: waves 0-2 get 3 (no xe duty), waves 3-7 get 2 (+ xe duty)
    const int nt = (w < 3) ? 3 : 2;
    const int t0 = (w < 3) ? 3 * w : 2 * w + 3;

    // zero both u buffers (zeros at k=100..111, 412..447 must persist)
    for (int i = tid; i < 2 * FRB * 512 / 2; i += 512) ((unsigned int*)uf)[i] = 0u;

    // ---- W resident in registers (A-operand: lane ln15 = row n, k = kk*32+q*8+j)
    half8   Wb[NTMAX][NFRAG];
    floatx4 biasv[NTMAX];
#pragma unroll
    for (int tt = 0; tt < NTMAX; ++tt) {
        const int nb = (t0 + tt) * 16;
#pragma unroll
        for (int r = 0; r < 4; ++r) {
            const int col = nb + 4 * q + r;
            biasv[tt][r] = (col < HID) ? (b_ih[col] + b_hh[col]) : 0.0f;
        }
        const int n = nb + ln15;
#pragma unroll
        for (int kk = 0; kk < NFRAG; ++kk) {
            union { half8 h; unsigned int d[4]; } cv;
#pragma unroll
            for (int j = 0; j < 8; ++j) {
                const int k = kk * 32 + q * 8 + j;
                float v = 0.0f;
                if (n < HID) {
                    if (k < EMB)                        v = W_ih[n * EMB + k];
                    else if (k >= 112 && k < 112 + HID) v = W_hh[n * HID + (k - 112)];
                }
                cv.h[j] = (_Float16)v;
            }
            asm volatile("" : "+v"(cv.d[0]), "+v"(cv.d[1]), "+v"(cv.d[2]), "+v"(cv.d[3]));
            Wb[tt][kk] = cv.h;
        }
    }

    // ---- precomputed LDS byte offsets
    char* ub = (char*)uf;
    const int rdo = lane * 16;
    int hwo[NTMAX];
#pragma unroll
    for (int tt = 0; tt < NTMAX; ++tt)
        hwo[tt] = fragoff(ln15, 112 + (t0 + tt) * 16 + 4 * q);

    // xe stager: threads 192..511 handle chunk sc; threads 192..271 also sc+320
    const bool st  = (tid >= 192);
    const int  sc  = tid - 192;
    const bool st2 = st && (sc < 80);
    const int  c1  = sc + 320;
    const int  gr0 = sc / 25, gc0 = sc - gr0 * 25;
    const int  gr1 = c1 / 25, gc1 = c1 - gr1 * 25;
    const int  xwo0 = fragoff(gr0 & 15, gc0 * 4);
    const int  xwo1 = fragoff(gr1 & 15, gc1 * 4);
    __syncthreads();

    // ---- xe for t=0 into buffer 0
    if (st) {
        const int idx = x[row0 + gr0];
        const float4 f = ((const float4*)emb)[(size_t)idx * 25 + gc0];
        half4h hv; hv[0] = (_Float16)f.x; hv[1] = (_Float16)f.y;
                   hv[2] = (_Float16)f.z; hv[3] = (_Float16)f.w;
        *(half4h*)(ub + xwo0) = hv;
    }
    if (st2) {
        const int idx = x[row0 + gr1];
        const float4 f = ((const float4*)emb)[(size_t)idx * 25 + gc1];
        half4h hv; hv[0] = (_Float16)f.x; hv[1] = (_Float16)f.y;
                   hv[2] = (_Float16)f.z; hv[3] = (_Float16)f.w;
        *(half4h*)(ub + xwo1) = hv;
    }
    __syncthreads();

#pragma unroll 2
    for (int t = 0; t < SEQ; ++t) {
        const int p = t & 1;
        const char* rb = ub + p * BUFB + rdo;
        char*       wb = ub + (1 - p) * BUFB;

        // issue xe_{t+1} gather first — vmcnt wait lands after the MFMA phase
        float4 pf0, pf1;
        const bool has = (t + 1 < SEQ);
        if (st && has) {
            const int idx = x[(size_t)(t + 1) * BATCH + row0 + gr0];
            pf0 = ((const float4*)emb)[(size_t)idx * 25 + gc0];
        }
        if (st2 && has) {
            const int idx = x[(size_t)(t + 1) * BATCH + row0 + gr1];
            pf1 = ((const float4*)emb)[(size_t)idx * 25 + gc1];
        }

        floatx4 acc[NTMAX];
#pragma unroll
        for (int tt = 0; tt < NTMAX; ++tt) acc[tt] = biasv[tt];

        // pipelined frag reads (single base + immediate offsets, conflict-free)
        half8 af[NFRAG];
#pragma unroll
        for (int kk = 0; kk < PD; ++kk) af[kk] = *(const half8*)(rb + kk * FB);
#pragma unroll
        for (int kk = 0; kk < NFRAG; ++kk) {
            if (kk + PD < NFRAG) af[kk + PD] = *(const half8*)(rb + (kk + PD) * FB);
#pragma unroll
            for (int tt = 0; tt < NTMAX; ++tt)
                if (tt < nt)   // wave-uniform
                    acc[tt] = __builtin_amdgcn_mfma_f32_16x16x32_f16(Wb[tt][kk], af[kk], acc[tt], 0, 0, 0);
        }

        // write xe_{t+1} into the next buffer
        if (st && has) {
            half4h hv; hv[0] = (_Float16)pf0.x; hv[1] = (_Float16)pf0.y;
                       hv[2] = (_Float16)pf0.z; hv[3] = (_Float16)pf0.w;
            *(half4h*)(wb + xwo0) = hv;
        }
        if (st2 && has) {
            half4h hv; hv[0] = (_Float16)pf1.x; hv[1] = (_Float16)pf1.y;
                       hv[2] = (_Float16)pf1.z; hv[3] = (_Float16)pf1.w;
            *(half4h*)(wb + xwo1) = hv;
        }
        // tanh + packed h-writes (D transposed: lane ln15 = batch row, 4 consecutive cols)
#pragma unroll
        for (int tt = 0; tt < NTMAX; ++tt) {
            if (tt < nt) {
                half4h hv;
#pragma unroll
                for (int r = 0; r < 4; ++r) hv[r] = (_Float16)fast_tanh(acc[tt][r]);
                *(half4h*)(wb + hwo[tt]) = hv;
            }
        }
        __syncthreads();   // single barrier per step
    }

    // ---- head: h1 = relu(h @ W1^T + b1); final h in buffer 0 (frag layout)
    {
        const int hro = fragoff(ln15, 112 + q * 8);
        floatx4 hacc[2];
        int ncol[2];
#pragma unroll
        for (int tt = 0; tt < 2; ++tt) {
            const int n = (w * 2 + tt) * 16 + ln15;
            ncol[tt] = n;
            const float b = b1[n];
            hacc[tt][0] = b; hacc[tt][1] = b; hacc[tt][2] = b; hacc[tt][3] = b;
        }
#pragma unroll
        for (int kk = 0; kk < NHF; ++kk) {
            const half8 a = *(const half8*)(ub + hro + kk * FB);
#pragma unroll
            for (int tt = 0; tt < 2; ++tt) {
                half8 bv;
#pragma unroll
                for (int j = 0; j < 8; ++j) {
                    const int k = kk * 32 + q * 8 + j;
                    bv[j] = (_Float16)((k < HID) ? W1[ncol[tt] * HID + k] : 0.0f);
                }
                hacc[tt] = __builtin_amdgcn_mfma_f32_16x16x32_f16(bv, a, hacc[tt], 0, 0, 0);
            }
        }
        // D transposed: lane ln15 = batch row, cols (2w+tt)*16 + 4q + r
#pragma unroll
        for (int tt = 0; tt < 2; ++tt) {
            float4 fv;
            fv.x = fmaxf(hacc[tt][0], 0.0f); fv.y = fmaxf(hacc[tt][1], 0.0f);
            fv.z = fmaxf(hacc[tt][2], 0.0f); fv.w = fmaxf(hacc[tt][3], 0.0f);
            *(float4*)&h1s[ln15][(w * 2 + tt) * 16 + 4 * q] = fv;
        }
    }
    __syncthreads();

    // ---- out = h1 @ W2^T + b2: 16 rows x 2 cols
    if (tid < 32) {
        const int r = tid & 15, o = tid >> 4;
        float a = b2[o];
        const float* ww = W2 + (size_t)o * NH1;
        for (int k = 0; k < NH1; ++k) a += h1s[r][k] * ww[k];
        out[(size_t)(row0 + r) * 2 + o] = a;
    }
}

extern "C" void kernel_launch(void* const* d_in, const int* in_sizes, int n_in,
                              void* d_out, int out_size, void* d_ws, size_t ws_size,
                              hipStream_t stream) {
    const int*   x    = (const int*)d_in[0];
    const float* emb  = (const float*)d_in[1];
    const float* W_ih = (const float*)d_in[2];
    const float* b_ih = (const float*)d_in[3];
    const float* W_hh = (const float*)d_in[4];
    const float* b_hh = (const float*)d_in[5];
    const float* W1   = (const float*)d_in[6];
    const float* b1   = (const float*)d_in[7];
    const float* W2   = (const float*)d_in[8];
    const float* b2   = (const float*)d_in[9];
    float* outp = (float*)d_out;

    hipLaunchKernelGGL(rnn_fused, dim3(BATCH / BM), dim3(512), 0, stream,
                       x, emb, W_ih, b_ih, W_hh, b_hh, W1, b1, W2, b2, outp);
}

// Round 9
// 366.794 us; speedup vs baseline: 1.3063x; 1.2218x over previous
//
#include <hip/hip_runtime.h>

#define SEQ   200
#define BATCH 4096
#define EMB   100
#define HID   300
#define NH1   256
#define BM    16
#define NFRAG 13             // K = 416: xe k=0..99 | zeros 100..111 | h k=112..411 | zeros
#define FRB   14             // allocated frag blocks (k up to 447)
#define FB    1024           // bytes per frag block (32 k x 16 rows x 2B)
#define BUFB  (FRB * FB)
#define NTMAX 3
#define NHF   10
#define H1P   260
#define PD    8              // LDS read-pipeline depth

typedef _Float16 half8 __attribute__((ext_vector_type(8)));
typedef _Float16 half4h __attribute__((ext_vector_type(4)));
typedef float floatx4 __attribute__((ext_vector_type(4)));

__device__ __forceinline__ float fast_tanh(float x) {
    float e = __expf(2.0f * x);
    float r = __builtin_amdgcn_rcpf(e + 1.0f);
    return 1.0f - 2.0f * r;
}

// frag-space byte offset of (batch row m, combined-k k)
__device__ __forceinline__ int fragoff(int m, int k) {
    return (k >> 5) * FB + ((k >> 3) & 3) * 256 + m * 16 + (k & 7) * 2;
}

// One straight-line recurrent loop, NTT = compile-time tiles/wave (no branches in body)
#define T_LOOP(NTT)                                                                   \
    _Pragma("unroll 2")                                                               \
    for (int t = 0; t < SEQ; ++t) {                                                   \
        const int p = t & 1;                                                          \
        const char* rb = ub + p * BUFB + rdo;                                         \
        char*       wb = ub + (1 - p) * BUFB;                                         \
        float4 pf;                                                                    \
        const bool hasx = (t + 1 < SEQ) && is_st;                                     \
        if (hasx) {                                                                   \
            const int idx = xs[(t + 1) * BM + gr];                                    \
            pf = ((const float4*)emb)[(size_t)idx * 25 + gc];                         \
        }                                                                             \
        floatx4 acc[NTT];                                                             \
        _Pragma("unroll")                                                             \
        for (int tt = 0; tt < NTT; ++tt) acc[tt] = biasv[tt];                         \
        half8 af[NFRAG];                                                              \
        _Pragma("unroll")                                                             \
        for (int kk = 0; kk < PD; ++kk) af[kk] = *(const half8*)(rb + kk * FB);       \
        _Pragma("unroll")                                                             \
        for (int kk = 0; kk < NFRAG; ++kk) {                                          \
            if (kk + PD < NFRAG) af[kk + PD] = *(const half8*)(rb + (kk + PD) * FB);  \
            _Pragma("unroll")                                                         \
            for (int tt = 0; tt < NTT; ++tt)                                          \
                acc[tt] = __builtin_amdgcn_mfma_f32_16x16x32_f16(Wb[tt][kk], af[kk],  \
                                                                 acc[tt], 0, 0, 0);   \
        }                                                                             \
        if (hasx) {                                                                   \
            half4h hv; hv[0] = (_Float16)pf.x; hv[1] = (_Float16)pf.y;                \
                       hv[2] = (_Float16)pf.z; hv[3] = (_Float16)pf.w;                \
            *(half4h*)(wb + xwo) = hv;                                                \
        }                                                                             \
        _Pragma("unroll")                                                             \
        for (int tt = 0; tt < NTT; ++tt) {                                            \
            half4h hv;                                                                \
            _Pragma("unroll")                                                         \
            for (int r = 0; r < 4; ++r) hv[r] = (_Float16)fast_tanh(acc[tt][r]);      \
            *(half4h*)(wb + hwo[tt]) = hv;                                            \
        }                                                                             \
        __syncthreads();                                                              \
    }

__global__ void __launch_bounds__(512)
rnn_fused(const int* __restrict__ x, const float* __restrict__ emb,
          const float* __restrict__ W_ih, const float* __restrict__ b_ih,
          const float* __restrict__ W_hh, const float* __restrict__ b_hh,
          const float* __restrict__ W1, const float* __restrict__ b1,
          const float* __restrict__ W2, const float* __restrict__ b2,
          float* __restrict__ out)
{
    __shared__ __align__(16) _Float16 uf[2][FRB][512];  // frag-order, double-buffered
    __shared__ int   xs[SEQ * BM];
    __shared__ float h1s[BM][H1P];

    const int tid  = threadIdx.x;
    const int lane = tid & 63;
    const int w    = tid >> 6;
    const int ln15 = lane & 15;
    const int q    = lane >> 4;
    const int row0 = blockIdx.x * BM;

    // 19 tiles of 16 cols: waves 0-2 get 3, waves 3-7 get 2
    const int nt = (w < 3) ? 3 : 2;
    const int t0 = (w < 3) ? 3 * w : 2 * w + 3;

    for (int i = tid; i < 2 * FRB * 512 / 2; i += 512) ((unsigned int*)uf)[i] = 0u;
    for (int i = tid; i < SEQ * BM; i += 512)
        xs[i] = x[(size_t)(i >> 4) * BATCH + row0 + (i & 15)];

    // ---- W resident in registers (A-operand: lane ln15 = row n, k = kk*32+q*8+j)
    half8   Wb[NTMAX][NFRAG];
    floatx4 biasv[NTMAX];
#pragma unroll
    for (int tt = 0; tt < NTMAX; ++tt) {
        const int nb = (t0 + tt) * 16;
#pragma unroll
        for (int r = 0; r < 4; ++r) {
            const int col = nb + 4 * q + r;
            biasv[tt][r] = (col < HID) ? (b_ih[col] + b_hh[col]) : 0.0f;
        }
        const int n = nb + ln15;
#pragma unroll
        for (int kk = 0; kk < NFRAG; ++kk) {
            union { half8 h; unsigned int d[4]; } cv;
#pragma unroll
            for (int j = 0; j < 8; ++j) {
                const int k = kk * 32 + q * 8 + j;
                float v = 0.0f;
                if (n < HID) {
                    if (k < EMB)                        v = W_ih[n * EMB + k];
                    else if (k >= 112 && k < 112 + HID) v = W_hh[n * HID + (k - 112)];
                }
                cv.h[j] = (_Float16)v;
            }
            asm volatile("" : "+v"(cv.d[0]), "+v"(cv.d[1]), "+v"(cv.d[2]), "+v"(cv.d[3]));
            Wb[tt][kk] = cv.h;
        }
    }

    // ---- precomputed LDS byte offsets
    char* ub = (char*)uf;
    const int rdo = lane * 16;
    int hwo[NTMAX];
#pragma unroll
    for (int tt = 0; tt < NTMAX; ++tt)
        hwo[tt] = fragoff(ln15, 112 + (t0 + tt) * 16 + 4 * q);

    // xe stager: threads 0..399, one float4 chunk each (spread over waves 0-6)
    const bool is_st = (tid < 400);
    const int  gr = tid / 25, gc = tid - gr * 25;
    const int  xwo = fragoff(gr & 15, gc * 4);
    __syncthreads();

    // ---- xe for t=0 into buffer 0
    if (is_st) {
        const int idx = xs[gr];
        const float4 f = ((const float4*)emb)[(size_t)idx * 25 + gc];
        half4h hv; hv[0] = (_Float16)f.x; hv[1] = (_Float16)f.y;
                   hv[2] = (_Float16)f.z; hv[3] = (_Float16)f.w;
        *(half4h*)(ub + xwo) = hv;
    }
    __syncthreads();

    if (w < 3) {
        T_LOOP(3)
    } else {
        T_LOOP(2)
    }

    // ---- head: h1 = relu(h @ W1^T + b1); final h in buffer 0 (frag layout)
    {
        const int hro = fragoff(ln15, 112 + q * 8);
        floatx4 hacc[2];
        int ncol[2];
#pragma unroll
        for (int tt = 0; tt < 2; ++tt) {
            const int n = (w * 2 + tt) * 16 + ln15;
            ncol[tt] = n;
            const float b = b1[n];
            hacc[tt][0] = b; hacc[tt][1] = b; hacc[tt][2] = b; hacc[tt][3] = b;
        }
#pragma unroll
        for (int kk = 0; kk < NHF; ++kk) {
            const half8 a = *(const half8*)(ub + hro + kk * FB);
#pragma unroll
            for (int tt = 0; tt < 2; ++tt) {
                half8 bv;
#pragma unroll
                for (int j = 0; j < 8; ++j) {
                    const int k = kk * 32 + q * 8 + j;
                    bv[j] = (_Float16)((k < HID) ? W1[ncol[tt] * HID + k] : 0.0f);
                }
                hacc[tt] = __builtin_amdgcn_mfma_f32_16x16x32_f16(bv, a, hacc[tt], 0, 0, 0);
            }
        }
        // D transposed: lane ln15 = batch row, cols (2w+tt)*16 + 4q + r
#pragma unroll
        for (int tt = 0; tt < 2; ++tt) {
            float4 fv;
            fv.x = fmaxf(hacc[tt][0], 0.0f); fv.y = fmaxf(hacc[tt][1], 0.0f);
            fv.z = fmaxf(hacc[tt][2], 0.0f); fv.w = fmaxf(hacc[tt][3], 0.0f);
            *(float4*)&h1s[ln15][(w * 2 + tt) * 16 + 4 * q] = fv;
        }
    }
    __syncthreads();

    // ---- out = h1 @ W2^T + b2: 16 rows x 2 cols
    if (tid < 32) {
        const int r = tid & 15, o = tid >> 4;
        float a = b2[o];
        const float* ww = W2 + (size_t)o * NH1;
        for (int k = 0; k < NH1; ++k) a += h1s[r][k] * ww[k];
        out[(size_t)(row0 + r) * 2 + o] = a;
    }
}

extern "C" void kernel_launch(void* const* d_in, const int* in_sizes, int n_in,
                              void* d_out, int out_size, void* d_ws, size_t ws_size,
                              hipStream_t stream) {
    const int*   x    = (const int*)d_in[0];
    const float* emb  = (const float*)d_in[1];
    const float* W_ih = (const float*)d_in[2];
    const float* b_ih = (const float*)d_in[3];
    const float* W_hh = (const float*)d_in[4];
    const float* b_hh = (const float*)d_in[5];
    const float* W1   = (const float*)d_in[6];
    const float* b1   = (const float*)d_in[7];
    const float* W2   = (const float*)d_in[8];
    const float* b2   = (const float*)d_in[9];
    float* outp = (float*)d_out;

    hipLaunchKernelGGL(rnn_fused, dim3(BATCH / BM), dim3(512), 0, stream,
                       x, emb, W_ih, b_ih, W_hh, b_hh, W1, b1, W2, b2, outp);
}

// Round 10
// 362.603 us; speedup vs baseline: 1.3214x; 1.0116x over previous
//
#include <hip/hip_runtime.h>

#define SEQ   200
#define BATCH 4096
#define EMB   100
#define HID   300
#define NH1   256
#define BM    16
#define NFRAG 13             // K = 416: xe k=0..99 | zeros 100..111 | h k=112..411 | zeros
#define FRB   14             // allocated frag blocks (k up to 447)
#define FB    1024           // bytes per frag block (32 k x 16 rows x 2B)
#define BUFB  (FRB * FB)
#define NTMAX 3
#define NHF   10
#define H1P   260
#define PD    10             // LDS read-pipeline depth

typedef _Float16 half8 __attribute__((ext_vector_type(8)));
typedef _Float16 half4h __attribute__((ext_vector_type(4)));
typedef float floatx4 __attribute__((ext_vector_type(4)));

__device__ __forceinline__ float fast_tanh(float x) {
    float e = __expf(2.0f * x);
    float r = __builtin_amdgcn_rcpf(e + 1.0f);
    return 1.0f - 2.0f * r;
}

// frag-space byte offset of (batch row m, combined-k k)
__device__ __forceinline__ int fragoff(int m, int k) {
    return (k >> 5) * FB + ((k >> 3) & 3) * 256 + m * 16 + (k & 7) * 2;
}

// One straight-line recurrent loop, NTT = compile-time tiles/wave (no branches in body)
#define T_LOOP(NTT)                                                                   \
    _Pragma("unroll 2")                                                               \
    for (int t = 0; t < SEQ; ++t) {                                                   \
        const int p = t & 1;                                                          \
        const char* rb = ub + p * BUFB + rdo;                                         \
        char*       wb = ub + (1 - p) * BUFB;                                         \
        float4 pf;                                                                    \
        const bool hasx = (t + 1 < SEQ) && is_st;                                     \
        if (hasx) {                                                                   \
            const int idx = xs[(t + 1) * BM + gr];                                    \
            pf = ((const float4*)emb)[(size_t)idx * 25 + gc];                         \
        }                                                                             \
        floatx4 acc[NTT];                                                             \
        _Pragma("unroll")                                                             \
        for (int tt = 0; tt < NTT; ++tt) acc[tt] = biasv[tt];                         \
        half8 af[NFRAG];                                                              \
        _Pragma("unroll")                                                             \
        for (int kk = 0; kk < PD; ++kk) af[kk] = *(const half8*)(rb + kk * FB);       \
        _Pragma("unroll")                                                             \
        for (int kk = 0; kk < NFRAG; ++kk) {                                          \
            if (kk + PD < NFRAG) af[kk + PD] = *(const half8*)(rb + (kk + PD) * FB);  \
            _Pragma("unroll")                                                         \
            for (int tt = 0; tt < NTT; ++tt)                                          \
                acc[tt] = __builtin_amdgcn_mfma_f32_16x16x32_f16(Wb[tt][kk], af[kk],  \
                                                                 acc[tt], 0, 0, 0);   \
        }                                                                             \
        _Pragma("unroll")                                                             \
        for (int tt = 0; tt < NTT; ++tt) {                                            \
            half4h hv;                                                                \
            _Pragma("unroll")                                                         \
            for (int r = 0; r < 4; ++r) hv[r] = (_Float16)fast_tanh(acc[tt][r]);      \
            *(half4h*)(wb + hwo[tt]) = hv;                                            \
        }                                                                             \
        if (hasx) {                                                                   \
            half4h hv; hv[0] = (_Float16)pf.x; hv[1] = (_Float16)pf.y;                \
                       hv[2] = (_Float16)pf.z; hv[3] = (_Float16)pf.w;                \
            *(half4h*)(wb + xwo) = hv;                                                \
        }                                                                             \
        __syncthreads();                                                              \
    }

__global__ void __launch_bounds__(512)
rnn_fused(const int* __restrict__ x, const float* __restrict__ emb,
          const float* __restrict__ W_ih, const float* __restrict__ b_ih,
          const float* __restrict__ W_hh, const float* __restrict__ b_hh,
          const float* __restrict__ W1, const float* __restrict__ b1,
          const float* __restrict__ W2, const float* __restrict__ b2,
          float* __restrict__ out)
{
    __shared__ __align__(16) _Float16 uf[2][FRB][512];  // frag-order, double-buffered
    __shared__ int   xs[SEQ * BM];
    __shared__ float h1s[BM][H1P];

    const int tid  = threadIdx.x;
    const int lane = tid & 63;
    const int w    = tid >> 6;
    const int ln15 = lane & 15;
    const int q    = lane >> 4;
    const int row0 = blockIdx.x * BM;

    // 19 tiles of 16 cols: waves 0-2 get 3, waves 3-7 get 2
    const int t0 = (w < 3) ? 3 * w : 2 * w + 3;

    for (int i = tid; i < 2 * FRB * 512 / 2; i += 512) ((unsigned int*)uf)[i] = 0u;
    for (int i = tid; i < SEQ * BM; i += 512)
        xs[i] = x[(size_t)(i >> 4) * BATCH + row0 + (i & 15)];

    // ---- W resident in registers (A-operand: lane ln15 = row n, k = kk*32+q*8+j)
    half8   Wb[NTMAX][NFRAG];
    floatx4 biasv[NTMAX];
#pragma unroll
    for (int tt = 0; tt < NTMAX; ++tt) {
        const int nb = (t0 + tt) * 16;
#pragma unroll
        for (int r = 0; r < 4; ++r) {
            const int col = nb + 4 * q + r;
            biasv[tt][r] = (col < HID) ? (b_ih[col] + b_hh[col]) : 0.0f;
        }
        const int n = nb + ln15;
#pragma unroll
        for (int kk = 0; kk < NFRAG; ++kk) {
            union { half8 h; unsigned int d[4]; } cv;
#pragma unroll
            for (int j = 0; j < 8; ++j) {
                const int k = kk * 32 + q * 8 + j;
                float v = 0.0f;
                if (n < HID) {
                    if (k < EMB)                        v = W_ih[n * EMB + k];
                    else if (k >= 112 && k < 112 + HID) v = W_hh[n * HID + (k - 112)];
                }
                cv.h[j] = (_Float16)v;
            }
            asm volatile("" : "+v"(cv.d[0]), "+v"(cv.d[1]), "+v"(cv.d[2]), "+v"(cv.d[3]));
            Wb[tt][kk] = cv.h;
        }
    }

    // ---- precomputed LDS byte offsets
    char* ub = (char*)uf;
    const int rdo = lane * 16;
    int hwo[NTMAX];
#pragma unroll
    for (int tt = 0; tt < NTMAX; ++tt)
        hwo[tt] = fragoff(ln15, 112 + (t0 + tt) * 16 + 4 * q);

    // xe stager: threads 0..399, one float4 chunk each (spread over waves 0-6)
    const bool is_st = (tid < 400);
    const int  gr = tid / 25, gc = tid - gr * 25;
    const int  xwo = fragoff(gr & 15, gc * 4);
    __syncthreads();

    // ---- xe for t=0 into buffer 0
    if (is_st) {
        const int idx = xs[gr];
        const float4 f = ((const float4*)emb)[(size_t)idx * 25 + gc];
        half4h hv; hv[0] = (_Float16)f.x; hv[1] = (_Float16)f.y;
                   hv[2] = (_Float16)f.z; hv[3] = (_Float16)f.w;
        *(half4h*)(ub + xwo) = hv;
    }
    __syncthreads();

    if (w < 3) {
        T_LOOP(3)
    } else {
        T_LOOP(2)
    }

    // ---- head: h1 = relu(h @ W1^T + b1); final h in buffer 0 (frag layout)
    {
        const int hro = fragoff(ln15, 112 + q * 8);
        floatx4 hacc[2];
        int ncol[2];
#pragma unroll
        for (int tt = 0; tt < 2; ++tt) {
            const int n = (w * 2 + tt) * 16 + ln15;
            ncol[tt] = n;
            const float b = b1[n];
            hacc[tt][0] = b; hacc[tt][1] = b; hacc[tt][2] = b; hacc[tt][3] = b;
        }
#pragma unroll
        for (int kk = 0; kk < NHF; ++kk) {
            const half8 a = *(const half8*)(ub + hro + kk * FB);
#pragma unroll
            for (int tt = 0; tt < 2; ++tt) {
                half8 bv;
#pragma unroll
                for (int j = 0; j < 8; ++j) {
                    const int k = kk * 32 + q * 8 + j;
                    bv[j] = (_Float16)((k < HID) ? W1[ncol[tt] * HID + k] : 0.0f);
                }
                hacc[tt] = __builtin_amdgcn_mfma_f32_16x16x32_f16(bv, a, hacc[tt], 0, 0, 0);
            }
        }
        // D transposed: lane ln15 = batch row, cols (2w+tt)*16 + 4q + r
#pragma unroll
        for (int tt = 0; tt < 2; ++tt) {
            float4 fv;
            fv.x = fmaxf(hacc[tt][0], 0.0f); fv.y = fmaxf(hacc[tt][1], 0.0f);
            fv.z = fmaxf(hacc[tt][2], 0.0f); fv.w = fmaxf(hacc[tt][3], 0.0f);
            *(float4*)&h1s[ln15][(w * 2 + tt) * 16 + 4 * q] = fv;
        }
    }
    __syncthreads();

    // ---- out = h1 @ W2^T + b2: 16 rows x 2 cols
    if (tid < 32) {
        const int r = tid & 15, o = tid >> 4;
        float a = b2[o];
        const float* ww = W2 + (size_t)o * NH1;
        for (int k = 0; k < NH1; ++k) a += h1s[r][k] * ww[k];
        out[(size_t)(row0 + r) * 2 + o] = a;
    }
}

extern "C" void kernel_launch(void* const* d_in, const int* in_sizes, int n_in,
                              void* d_out, int out_size, void* d_ws, size_t ws_size,
                              hipStream_t stream) {
    const int*   x    = (const int*)d_in[0];
    const float* emb  = (const float*)d_in[1];
    const float* W_ih = (const float*)d_in[2];
    const float* b_ih = (const float*)d_in[3];
    const float* W_hh = (const float*)d_in[4];
    const float* b_hh = (const float*)d_in[5];
    const float* W1   = (const float*)d_in[6];
    const float* b1   = (const float*)d_in[7];
    const float* W2   = (const float*)d_in[8];
    const float* b2   = (const float*)d_in[9];
    float* outp = (float*)d_out;

    hipLaunchKernelGGL(rnn_fused, dim3(BATCH / BM), dim3(512), 0, stream,
                       x, emb, W_ih, b_ih, W_hh, b_hh, W1, b1, W2, b2, outp);
}